// Round 14
// baseline (149.354 us; speedup 1.0000x reference)
//
#include <hip/hip_runtime.h>
#include <cstdint>

// Bit-exact vs numpy reference: no FMA contraction anywhere in this TU.
#pragma clang fp contract(off)

#define NROWS 2000   // pred boxes per image
#define MCOLS 200    // gt boxes per image
#define BIMG  128    // images
#define NTHR  5      // thresholds 0.5..0.7 step 0.05
#define CAP   768    // per-image candidate entry capacity (expected ~76)
#define NPMAX 1024   // next pow2 >= CAP (LDS sort buffer)
#define GB    8      // 8x8 grid of 128px cells
#define NCELL (GB * GB)
#define PCHUNK 250   // preds per block (8 chunks x 250 = 2000)
#define NCHUNK (NROWS / PCHUNK)

// screening factor: inter >= t*uni  <=>  inter >= (t/(1+t))*(a1+a2).
// 0.4993/1.4993 = 0.333022 < 0.333200 = 0.4997/1.4997 -> every pair with
// exact IoU >= 0.4997 is flagged even with ~ulp predicate rounding.
#define CFAC 0.33302208f

typedef unsigned long long ull;

// --- Fused screen + (last-block) match + (last-image) finalize.
//     Block = (pred-chunk, image), 256 thr. Screen part identical to r13:
//     re-bin 200 gt into LDS SoA, each thread tests ONE pred against its 3x3
//     cell neighborhood (provable superset of inter>0: overlap needs
//     |dx1|<120 ∧ |dy1|<120 < 128). The LAST block of each image (global
//     atomic + device-scope fences, G16 pattern) sorts the image's keys and
//     replays the exact greedy; the LAST image's tail does the final mean.
//     Sort's total order erases all append/completion nondeterminism. ---
__global__ void __launch_bounds__(256) fused_kernel(
        const float4* __restrict__ pred, const float4* __restrict__ gt,
        int* __restrict__ counters, ull* __restrict__ entries,
        int* __restrict__ done_blocks, int* __restrict__ done_images,
        float* __restrict__ perimg, float* __restrict__ out) {
    __shared__ float gx[MCOLS], gy[MCOLS], gz[MCOLS], gw[MCOLS], ga2[MCOLS];
    __shared__ int   gid_l[MCOLS];
    __shared__ int   goff_l[NCELL + 1];
    __shared__ int   gcur[NCELL];
    __shared__ ull   keys[NPMAX];
    __shared__ float precs[NTHR];
    __shared__ int   flag;
    const int b = blockIdx.y, tid = threadIdx.x;

    // hoisted coalesced pred load (before the binning barriers)
    const int r = blockIdx.x * PCHUNK + (tid < PCHUNK ? tid : PCHUNK - 1);
    const float4 p = pred[(size_t)b * NROWS + r];

    if (tid < NCELL) gcur[tid] = 0;
    __syncthreads();

    // 1) load gt, count cells
    float4 gr = make_float4(0.f, 0.f, 0.f, 0.f);
    int gbn = -1;
    if (tid < MCOLS) {
        gr = gt[(size_t)b * MCOLS + tid];
        int cx = (int)gr.x >> 7, cy = (int)gr.y >> 7;
        cx = cx < 0 ? 0 : (cx > GB - 1 ? GB - 1 : cx);
        cy = cy < 0 ? 0 : (cy > GB - 1 ? GB - 1 : cy);
        gbn = cy * GB + cx;
        atomicAdd(&gcur[gbn], 1);
    }
    __syncthreads();

    // 2) exclusive scan over 64 cells in wave 0 (lane == cell)
    if (tid < 64) {
        const int v = gcur[tid];
        int inc = v;
#pragma unroll
        for (int off = 1; off < 64; off <<= 1) {
            const int u = __shfl_up(inc, off);
            if (tid >= off) inc += u;
        }
        goff_l[tid + 1] = inc;
        if (tid == 0) goff_l[0] = 0;
        gcur[tid] = inc - v;               // exclusive offset -> scatter cursor
    }
    __syncthreads();

    // 3) scatter gt into binned SoA order
    if (gbn >= 0) {
        const int idx = atomicAdd(&gcur[gbn], 1);
        gx[idx] = gr.x; gy[idx] = gr.y; gz[idx] = gr.z; gw[idx] = gr.w;
        ga2[idx] = (gr.z - gr.x) * (gr.w - gr.y);   // exact reference product
        gid_l[idx] = tid;
    }
    __syncthreads();

    // 4) screen: one pred per thread vs 3x3 neighborhood
    if (tid < PCHUNK) {
        const float a1 = (p.z - p.x) * (p.w - p.y);
        const float ca1 = CFAC * a1;
        int cx = (int)p.x >> 7, cy = (int)p.y >> 7;
        cx = cx < 0 ? 0 : (cx > GB - 1 ? GB - 1 : cx);
        cy = cy < 0 ? 0 : (cy > GB - 1 ? GB - 1 : cy);
        const int xlo = cx > 0 ? cx - 1 : 0;
        const int xhi = cx < GB - 1 ? cx + 1 : GB - 1;
        const int ylo = cy > 0 ? cy - 1 : 0;
        const int yhi = cy < GB - 1 ? cy + 1 : GB - 1;
        for (int gyy = ylo; gyy <= yhi; ++gyy) {
            const int lo = goff_l[gyy * GB + xlo];
            const int hi = goff_l[gyy * GB + xhi + 1];
            for (int j = lo; j < hi; ++j) {
                const float a2 = ga2[j];
                const float ltx = fmaxf(p.x, gx[j]), lty = fmaxf(p.y, gy[j]);
                const float rbx = fminf(p.z, gz[j]), rby = fminf(p.w, gw[j]);
                const float wx = fmaxf(rbx - ltx, 0.0f), wy = fmaxf(rby - lty, 0.0f);
                const float inter = wx * wy;
                if (inter >= ca1 + CFAC * a2) {             // rare
                    const float uni = (a1 + a2) - inter;    // reference order
                    const float iou = inter / uni;          // exact IEEE
                    const int idx = atomicAdd(&counters[b], 1);
                    if (idx < CAP)
                        entries[(size_t)b * CAP + idx] = ((ull)r << 40)
                            | ((ull)(__float_as_uint(iou) ^ 0xFFFFFFFFu) << 8)
                            | (ull)gid_l[j];
                }
            }
        }
    }

    // ---- last-block-done tail: this image's match ----
    __syncthreads();                        // all stores issued
    __threadfence();                        // release: entries -> device scope
    if (tid == 0)
        flag = (atomicAdd(&done_blocks[b], 1) == NCHUNK - 1) ? 1 : 0;
    __syncthreads();
    if (!flag) return;
    __threadfence();                        // acquire: see all blocks' entries

    const int n = min(atomicAdd(&counters[b], 0), CAP);   // atomic read
    int np = 256;
    while (np < n) np <<= 1;               // n<=768 -> np<=1024
    {
        volatile const ull* ep = entries + (size_t)b * CAP;
        for (int i = tid; i < np; i += 256)
            keys[i] = (i < n) ? ep[i] : ~0ull;             // sentinels last
    }
    __syncthreads();

    for (int k = 2; k <= np; k <<= 1) {
        for (int j = k >> 1; j > 0; j >>= 1) {
            for (int i = tid; i < np; i += 256) {
                const int ixj = i ^ j;
                if (ixj > i) {
                    const ull a = keys[i], c = keys[ixj];
                    if ((a > c) == ((i & k) == 0)) { keys[i] = c; keys[ixj] = a; }
                }
            }
            __syncthreads();
        }
    }

    if (tid < NTHR) {
        // match np.arange(0.5, 0.75, 0.05): start + i*step in double, cast f32
        const float thr = (float)(0.5 + 0.05 * (double)tid);
        const uint thr_inv = __float_as_uint(thr) ^ 0xFFFFFFFFu;
        ull m0 = 0, m1 = 0, m2 = 0, m3 = 0;
        int tp = 0, cur = -1;
        bool done = false;
#pragma unroll 4
        for (int e = 0; e < n; ++e) {
            const ull key = keys[e];
            const int row = (int)(key >> 40);
            const int col = (int)(key & 0xFFull);
            const uint ib  = (uint)(key >> 8);    // inverted iou bits
            const bool newrow = (row != cur);
            cur = row;
            const bool undecided = newrow || !done;
            const int w = col >> 6;
            const ull bit = 1ull << (col & 63);
            const ull mm = (w == 0) ? m0 : (w == 1) ? m1 : (w == 2) ? m2 : m3;
            const bool decide = undecided && ((mm & bit) == 0);  // best unmatched col
            const bool hit = decide && (ib <= thr_inv);          // iou >= thr
            tp += hit ? 1 : 0;
            const ull sb = hit ? bit : 0ull;
            m0 |= (w == 0) ? sb : 0ull;
            m1 |= (w == 1) ? sb : 0ull;
            m2 |= (w == 2) ? sb : 0ull;
            m3 |= (w == 3) ? sb : 0ull;
            done = decide || (done && !newrow);
        }
        // fp = NROWS - tp, fn = MCOLS - tp  =>  prec = tp / (N + M - tp)
        precs[tid] = (float)tp / (float)(NROWS + MCOLS - tp);
    }
    __syncthreads();
    if (tid == 0) {
        float s = 0.0f;
#pragma unroll
        for (int t = 0; t < NTHR; ++t) s += precs[t];
        perimg[b] = s / (float)NTHR;
    }

    // ---- last-image-done tail: final mean over images ----
    __syncthreads();
    __threadfence();                        // release perimg[b]
    if (tid == 0)
        flag = (atomicAdd(done_images, 1) == BIMG - 1) ? 1 : 0;
    __syncthreads();
    if (!flag) return;
    __threadfence();                        // acquire all perimg

    if (tid < 64) {                         // fixed-order reduce == old finalize
        volatile const float* pv = perimg;
        float s = pv[tid] + pv[tid + 64];
#pragma unroll
        for (int off = 32; off; off >>= 1) s += __shfl_xor(s, off);
        if (tid == 0) out[0] = s / (float)BIMG;
    }
}

extern "C" void kernel_launch(void* const* d_in, const int* in_sizes, int n_in,
                              void* d_out, int out_size, void* d_ws, size_t ws_size,
                              hipStream_t stream) {
    const float4* pred = (const float4*)d_in[0];
    const float4* gt   = (const float4*)d_in[1];
    float* out = (float*)d_out;

    // [counters 128 | done_blocks 128 | done_images 1] -> one memset region
    int*   cnt     = (int*)d_ws;
    int*   donebl  = cnt + BIMG;
    int*   doneim  = donebl + BIMG;
    ull*   entries = (ull*)((char*)d_ws + 2048);                   // 128*CAP u64
    float* perimg  = (float*)((char*)d_ws + 2048 + (size_t)BIMG * CAP * 8);

    (void)hipMemsetAsync(cnt, 0, (2 * BIMG + 1) * sizeof(int), stream);

    fused_kernel<<<dim3(NCHUNK, BIMG), dim3(256), 0, stream>>>(
        pred, gt, cnt, entries, donebl, doneim, perimg, out);
}

// Round 15
// 53.358 us; speedup vs baseline: 2.7991x; 2.7991x over previous
//
#include <hip/hip_runtime.h>
#include <cstdint>

// Bit-exact vs numpy reference: no FMA contraction anywhere in this TU.
#pragma clang fp contract(off)

#define NROWS 2000   // pred boxes per image
#define MCOLS 200    // gt boxes per image
#define BIMG  128    // images
#define NTHR  5      // thresholds 0.5..0.7 step 0.05
#define NPMAX 1024   // LDS sort buffer (>= NCHUNK*SCAP)
#define GB    8      // 8x8 grid of 128px cells
#define NCELL (GB * GB)
#define PCHUNK 250   // preds per block (8 chunks x 250 = 2000)
#define NCHUNK (NROWS / PCHUNK)
#define SCAP  96     // per-(block,image) entry slice capacity (expected ~10)

// screening factor: inter >= t*uni  <=>  inter >= (t/(1+t))*(a1+a2).
// 0.4993/1.4993 = 0.333022 < 0.333200 = 0.4997/1.4997 -> every pair with
// exact IoU >= 0.4997 is flagged even with ~ulp predicate rounding.
#define CFAC 0.33302208f

typedef unsigned long long ull;

// --- Phase 1: screen. Block = (pred-chunk, image), 256 thr. Re-bins the 200
//     gt into LDS SoA, each thread tests ONE pred against its 3x3 cell
//     neighborhood (provable superset of inter>0 pairs: overlap needs
//     |dx1|<120 ∧ |dy1|<120, both < 128; excluded pairs have inter==0).
//     Hits append into the block's OWN 96-entry slice via an LDS counter —
//     no global atomics, no memset dependency; slice fill order is erased by
//     match's total-order sort. Block (0,0) zeroes done_images for phase 2. ---
__global__ void __launch_bounds__(256) screen_kernel(
        const float4* __restrict__ pred, const float4* __restrict__ gt,
        ull* __restrict__ entries, int* __restrict__ blkcnt,
        int* __restrict__ done_images) {
    __shared__ float gx[MCOLS], gy[MCOLS], gz[MCOLS], gw[MCOLS], ga2[MCOLS];
    __shared__ int   gid_l[MCOLS];
    __shared__ int   goff_l[NCELL + 1];
    __shared__ int   gcur[NCELL];
    __shared__ int   lcnt;
    const int b = blockIdx.y, tid = threadIdx.x;

    if (blockIdx.x == 0 && b == 0 && tid == 0) *done_images = 0;

    // hoisted coalesced pred load (overlaps the binning barriers)
    const int r = blockIdx.x * PCHUNK + (tid < PCHUNK ? tid : PCHUNK - 1);
    const float4 p = pred[(size_t)b * NROWS + r];

    if (tid < NCELL) gcur[tid] = 0;
    if (tid == 0) lcnt = 0;
    __syncthreads();

    // 1) load gt, count cells
    float4 gr = make_float4(0.f, 0.f, 0.f, 0.f);
    int gbn = -1;
    if (tid < MCOLS) {
        gr = gt[(size_t)b * MCOLS + tid];
        int cx = (int)gr.x >> 7, cy = (int)gr.y >> 7;
        cx = cx < 0 ? 0 : (cx > GB - 1 ? GB - 1 : cx);
        cy = cy < 0 ? 0 : (cy > GB - 1 ? GB - 1 : cy);
        gbn = cy * GB + cx;
        atomicAdd(&gcur[gbn], 1);
    }
    __syncthreads();

    // 2) exclusive scan over 64 cells in wave 0 (lane == cell)
    if (tid < 64) {
        const int v = gcur[tid];
        int inc = v;
#pragma unroll
        for (int off = 1; off < 64; off <<= 1) {
            const int u = __shfl_up(inc, off);
            if (tid >= off) inc += u;
        }
        goff_l[tid + 1] = inc;
        if (tid == 0) goff_l[0] = 0;
        gcur[tid] = inc - v;               // exclusive offset -> scatter cursor
    }
    __syncthreads();

    // 3) scatter gt into binned SoA order
    if (gbn >= 0) {
        const int idx = atomicAdd(&gcur[gbn], 1);
        gx[idx] = gr.x; gy[idx] = gr.y; gz[idx] = gr.z; gw[idx] = gr.w;
        ga2[idx] = (gr.z - gr.x) * (gr.w - gr.y);   // exact reference product
        gid_l[idx] = tid;
    }
    __syncthreads();

    // 4) screen: one pred per thread vs 3x3 neighborhood
    ull* __restrict__ slice = entries + (size_t)(b * NCHUNK + blockIdx.x) * SCAP;
    if (tid < PCHUNK) {
        const float a1 = (p.z - p.x) * (p.w - p.y);
        const float ca1 = CFAC * a1;
        int cx = (int)p.x >> 7, cy = (int)p.y >> 7;
        cx = cx < 0 ? 0 : (cx > GB - 1 ? GB - 1 : cx);
        cy = cy < 0 ? 0 : (cy > GB - 1 ? GB - 1 : cy);
        const int xlo = cx > 0 ? cx - 1 : 0;
        const int xhi = cx < GB - 1 ? cx + 1 : GB - 1;
        const int ylo = cy > 0 ? cy - 1 : 0;
        const int yhi = cy < GB - 1 ? cy + 1 : GB - 1;
        for (int gyy = ylo; gyy <= yhi; ++gyy) {
            const int lo = goff_l[gyy * GB + xlo];
            const int hi = goff_l[gyy * GB + xhi + 1];
            for (int j = lo; j < hi; ++j) {
                const float a2 = ga2[j];
                const float ltx = fmaxf(p.x, gx[j]), lty = fmaxf(p.y, gy[j]);
                const float rbx = fminf(p.z, gz[j]), rby = fminf(p.w, gw[j]);
                const float wx = fmaxf(rbx - ltx, 0.0f), wy = fmaxf(rby - lty, 0.0f);
                const float inter = wx * wy;
                if (inter >= ca1 + CFAC * a2) {             // rare
                    const float uni = (a1 + a2) - inter;    // reference order
                    const float iou = inter / uni;          // exact IEEE
                    const int idx = atomicAdd(&lcnt, 1);    // LDS atomic only
                    if (idx < SCAP)
                        slice[idx] = ((ull)r << 40)
                            | ((ull)(__float_as_uint(iou) ^ 0xFFFFFFFFu) << 8)
                            | (ull)gid_l[j];
                }
            }
        }
    }
    __syncthreads();
    if (tid == 0) blkcnt[b * NCHUNK + blockIdx.x] = min(lcnt, SCAP);
}

// --- Phase 2: per image: gather slices compactly, bitonic-sort keys
//     (deterministic total order erases append nondeterminism), 5 lanes
//     replay exact greedy branchlessly; LAST block (128-block done-counter,
//     single fence each) reduces the final mean. ---
__global__ void __launch_bounds__(256) match_kernel(
        const ull* __restrict__ entries, const int* __restrict__ blkcnt,
        int* __restrict__ done_images, float* __restrict__ perimg,
        float* __restrict__ out) {
    __shared__ ull   keys[NPMAX];
    __shared__ int   base[NCHUNK + 1];
    __shared__ float precs[NTHR];
    __shared__ int   flag;
    const int b = blockIdx.x;
    const int tid = threadIdx.x;

    if (tid == 0) {
        int s = 0;
#pragma unroll
        for (int c = 0; c < NCHUNK; ++c) {
            base[c] = s;
            s += blkcnt[b * NCHUNK + c];
        }
        base[NCHUNK] = s;
    }
    __syncthreads();
    const int n = base[NCHUNK];            // <= NCHUNK*SCAP = 768

    // compact gather of all slices
#pragma unroll
    for (int c = 0; c < NCHUNK; ++c) {
        const int lo = base[c], cnt = base[c + 1] - lo;
        for (int i = tid; i < cnt; i += 256)
            keys[lo + i] = entries[(size_t)(b * NCHUNK + c) * SCAP + i];
    }
    int np = 64;
    while (np < n) np <<= 1;               // n~76 -> np=128
    for (int i = tid; i < np; i += 256)
        if (i >= n) keys[i] = ~0ull;       // sentinels sort last
    __syncthreads();

    for (int k = 2; k <= np; k <<= 1) {
        for (int j = k >> 1; j > 0; j >>= 1) {
            for (int i = tid; i < np; i += 256) {
                const int ixj = i ^ j;
                if (ixj > i) {
                    const ull a = keys[i], c = keys[ixj];
                    if ((a > c) == ((i & k) == 0)) { keys[i] = c; keys[ixj] = a; }
                }
            }
            __syncthreads();
        }
    }

    if (tid < NTHR) {
        // match np.arange(0.5, 0.75, 0.05): start + i*step in double, cast f32
        const float thr = (float)(0.5 + 0.05 * (double)tid);
        const uint thr_inv = __float_as_uint(thr) ^ 0xFFFFFFFFu;
        ull m0 = 0, m1 = 0, m2 = 0, m3 = 0;
        int tp = 0, cur = -1;
        bool done = false;
#pragma unroll 4
        for (int e = 0; e < n; ++e) {
            const ull key = keys[e];
            const int row = (int)(key >> 40);
            const int col = (int)(key & 0xFFull);
            const uint ib  = (uint)(key >> 8);    // inverted iou bits (low = high iou)
            const bool newrow = (row != cur);
            cur = row;
            const bool undecided = newrow || !done;
            const int w = col >> 6;
            const ull bit = 1ull << (col & 63);
            const ull mm = (w == 0) ? m0 : (w == 1) ? m1 : (w == 2) ? m2 : m3;
            const bool decide = undecided && ((mm & bit) == 0);  // best unmatched col
            const bool hit = decide && (ib <= thr_inv);          // iou >= thr
            tp += hit ? 1 : 0;
            const ull sb = hit ? bit : 0ull;
            m0 |= (w == 0) ? sb : 0ull;
            m1 |= (w == 1) ? sb : 0ull;
            m2 |= (w == 2) ? sb : 0ull;
            m3 |= (w == 3) ? sb : 0ull;
            done = decide || (done && !newrow);
        }
        // fp = NROWS - tp, fn = MCOLS - tp  =>  prec = tp / (N + M - tp)
        precs[tid] = (float)tp / (float)(NROWS + MCOLS - tp);
    }
    __syncthreads();
    if (tid == 0) {
        float s = 0.0f;
#pragma unroll
        for (int t = 0; t < NTHR; ++t) s += precs[t];
        __hip_atomic_store(&perimg[b], s / (float)NTHR,
                           __ATOMIC_RELAXED, __HIP_MEMORY_SCOPE_AGENT);
    }

    // ---- last-block-done tail (128 blocks): final mean over images ----
    __syncthreads();
    __threadfence();                       // release perimg[b]
    if (tid == 0)
        flag = (atomicAdd(done_images, 1) == BIMG - 1) ? 1 : 0;
    __syncthreads();
    if (!flag) return;
    __threadfence();                       // acquire all perimg

    if (tid < 64) {                        // fixed-order reduce == old finalize
        const float v0 = __hip_atomic_load(&perimg[tid],
                           __ATOMIC_RELAXED, __HIP_MEMORY_SCOPE_AGENT);
        const float v1 = __hip_atomic_load(&perimg[tid + 64],
                           __ATOMIC_RELAXED, __HIP_MEMORY_SCOPE_AGENT);
        float s = v0 + v1;
#pragma unroll
        for (int off = 32; off; off >>= 1) s += __shfl_xor(s, off);
        if (tid == 0) out[0] = s / (float)BIMG;
    }
}

extern "C" void kernel_launch(void* const* d_in, const int* in_sizes, int n_in,
                              void* d_out, int out_size, void* d_ws, size_t ws_size,
                              hipStream_t stream) {
    const float4* pred = (const float4*)d_in[0];
    const float4* gt   = (const float4*)d_in[1];
    float* out = (float*)d_out;

    // workspace: [done 1 int | blkcnt 128*8 | perimg 128 f | entries 128*8*96 u64]
    int*   doneim  = (int*)d_ws;
    int*   blkcnt  = doneim + 64;                                  // aligned
    float* perimg  = (float*)(blkcnt + BIMG * NCHUNK);
    ull*   entries = (ull*)((char*)d_ws + 8192);

    screen_kernel<<<dim3(NCHUNK, BIMG), dim3(256), 0, stream>>>(
        pred, gt, entries, blkcnt, doneim);

    match_kernel<<<dim3(BIMG), dim3(256), 0, stream>>>(
        entries, blkcnt, doneim, perimg, out);
}